// Round 8
// baseline (299.153 us; speedup 1.0000x reference)
//
#include <hip/hip_runtime.h>

// ---------------------------------------------------------------------------
// AGNN: h = relu(x@W1^T+b1); 4x [ h = relu(agnn(h)) ]; out = h@W2^T+b2
// N=100000, E=1600000, IN=128, HID=OUT=64, float32 in/out.
// Between layers: xn = h/(||h||+eps) stored FP16 (128 B/row) + nrm f32.
//   p = exp2( dot(xn_i * log2e, xn_j) );  out_i = sum p * nrm_j * xn_j / sum p
// Round 8: agnn is at the HBM random-sector wall (97 MB/layer random 64B
//   sectors at ~2.4 TB/s ~= 40 us; 4 structural rewrites all landed 40+-1).
//   This round: gemm density. gemm1/gemm2 -> 256-node x 64-out tile,
//   512 threads, 8 nodes x 4 outs per thread (32 FMA per k-step vs
//   3 broadcast ds_read_b128 -> FMA-pipe bound), K-chunked with register
//   prefetch. agnn burst kernel (r7) + meta sort + rowptr scan unchanged.
// ---------------------------------------------------------------------------

typedef _Float16 h2 __attribute__((ext_vector_type(2)));

union U4H { uint4 u; h2 h[4]; };
union U2H { uint2 u; h2 h[2]; };
union UHI { unsigned u; h2 h; };
union UF  { unsigned u; float f; int i; };

#define DEV_INLINE __device__ __forceinline__

DEV_INLINE h2 mkh2(float a, float b) {
    h2 r; r.x = (_Float16)a; r.y = (_Float16)b; return r;
}

// x + dpp_perm(x): 0xB1 quad_perm xor1, 0x4E quad_perm xor2,
// 0x141 row_half_mirror (i^7 == xor4 after quads uniform),
// 0x140 row_mirror (i^15 == xor8 after 8-groups uniform).
template <int CTRL>
DEV_INLINE float dpp_addf(float x) {
    UF a, b;
    a.f = x;
    b.i = __builtin_amdgcn_update_dpp(0, a.i, CTRL, 0xF, 0xF, true);
    return x + b.f;
}

// ptr[i] = lower_bound(row, i). Thread e covers i in (row[e-1], row[e]].
__global__ __launch_bounds__(256) void build_rowptr_scan(const int* __restrict__ row,
                                                         int* __restrict__ ptr,
                                                         int N, int E) {
    int e = blockIdx.x * blockDim.x + threadIdx.x;
    if (e >= E) return;
    const int r1 = row[e];
    const int r0 = (e == 0) ? -1 : row[e - 1];
    for (int i = r0 + 1; i <= r1; ++i) ptr[i] = e;
    if (e == E - 1) {
        for (int i = r1 + 1; i <= N; ++i) ptr[i] = E;
    }
}

// Segment-local counting sort by degree; emits meta[pos] = (nid, p0, p1, 0).
#define PSEG 1024
__global__ __launch_bounds__(1024) void build_perm_seg(const int* __restrict__ ptr,
                                                       int4* __restrict__ meta,
                                                       int N) {
    __shared__ int hist[256];
    __shared__ int tmp[256];
    const int t    = threadIdx.x;
    const int base = blockIdx.x * PSEG;
    const int end  = (base + PSEG < N) ? base + PSEG : N;
    const int cnt  = end - base;

    if (t < 256) hist[t] = 0;
    __syncthreads();

    int d = -1, p0v = 0, p1v = 0;
    if (t < cnt) {
        p0v = ptr[base + t];
        p1v = ptr[base + t + 1];
        d = p1v - p0v;
        if (d > 255) d = 255;
        atomicAdd(&hist[d], 1);
    }
    __syncthreads();

    int h0 = (t < 256) ? hist[t] : 0;
    int* src = hist; int* dst = tmp;
    for (int off = 1; off < 256; off <<= 1) {
        if (t < 256) dst[t] = src[t] + (t >= off ? src[t - off] : 0);
        __syncthreads();
        int* tt = src; src = dst; dst = tt;
    }
    if (t < 256) src[t] -= h0;
    __syncthreads();

    if (t < cnt) {
        int pos = base + atomicAdd(&src[d], 1);
        meta[pos] = make_int4(base + t, p0v, p1v, 0);
    }
}

#define GEMM_BODY(w4, xa, xb)                                   \
    acc[0].x = fmaf(xa.x, w4.x, acc[0].x);                      \
    acc[0].y = fmaf(xa.x, w4.y, acc[0].y);                      \
    acc[0].z = fmaf(xa.x, w4.z, acc[0].z);                      \
    acc[0].w = fmaf(xa.x, w4.w, acc[0].w);                      \
    acc[1].x = fmaf(xa.y, w4.x, acc[1].x);                      \
    acc[1].y = fmaf(xa.y, w4.y, acc[1].y);                      \
    acc[1].z = fmaf(xa.y, w4.z, acc[1].z);                      \
    acc[1].w = fmaf(xa.y, w4.w, acc[1].w);                      \
    acc[2].x = fmaf(xa.z, w4.x, acc[2].x);                      \
    acc[2].y = fmaf(xa.z, w4.y, acc[2].y);                      \
    acc[2].z = fmaf(xa.z, w4.z, acc[2].z);                      \
    acc[2].w = fmaf(xa.z, w4.w, acc[2].w);                      \
    acc[3].x = fmaf(xa.w, w4.x, acc[3].x);                      \
    acc[3].y = fmaf(xa.w, w4.y, acc[3].y);                      \
    acc[3].z = fmaf(xa.w, w4.z, acc[3].z);                      \
    acc[3].w = fmaf(xa.w, w4.w, acc[3].w);                      \
    acc[4].x = fmaf(xb.x, w4.x, acc[4].x);                      \
    acc[4].y = fmaf(xb.x, w4.y, acc[4].y);                      \
    acc[4].z = fmaf(xb.x, w4.z, acc[4].z);                      \
    acc[4].w = fmaf(xb.x, w4.w, acc[4].w);                      \
    acc[5].x = fmaf(xb.y, w4.x, acc[5].x);                      \
    acc[5].y = fmaf(xb.y, w4.y, acc[5].y);                      \
    acc[5].z = fmaf(xb.y, w4.z, acc[5].z);                      \
    acc[5].w = fmaf(xb.y, w4.w, acc[5].w);                      \
    acc[6].x = fmaf(xb.z, w4.x, acc[6].x);                      \
    acc[6].y = fmaf(xb.z, w4.y, acc[6].y);                      \
    acc[6].z = fmaf(xb.z, w4.z, acc[6].z);                      \
    acc[6].w = fmaf(xb.z, w4.w, acc[6].w);                      \
    acc[7].x = fmaf(xb.w, w4.x, acc[7].x);                      \
    acc[7].y = fmaf(xb.w, w4.y, acc[7].y);                      \
    acc[7].z = fmaf(xb.w, w4.z, acc[7].z);                      \
    acc[7].w = fmaf(xb.w, w4.w, acc[7].w);

// r = relu(x[i,:128]@W1^T + b1); xn[i]=f16(r/(||r||+eps)); nrm[i]=||r||+eps
// 512 threads, tile 256 nodes x 64 outs, thread = 8 nodes x 4 outs.
// K in four 32-chunks, register prefetch of next chunk during compute.
__global__ __launch_bounds__(512) void gemm1_relu(const float* __restrict__ x,
                                                  const float* __restrict__ W1,
                                                  const float* __restrict__ b1,
                                                  unsigned short* __restrict__ xn,
                                                  float* __restrict__ nrm,
                                                  int N) {
    __shared__ __align__(16) float Wt[32 * 64];    // 8 KiB
    __shared__ __align__(16) float xT[32 * 256];   // 32 KiB
    const int tid  = threadIdx.x;
    const int tx   = tid & 15;    // 4 outs at 4*tx
    const int ty   = tid >> 4;    // 8 nodes at 8*ty, ty in [0,32)
    const int base = blockIdx.x * 256;

    const float4* W4  = (const float4*)W1;
    const float4* x4p = (const float4*)x;

    // staging indices
    const int wO  = tid & 63;          // W: output column
    const int wK4 = tid >> 6;          // W: k4 in [0,8)
    const int mA  = tid & 255;         // x: node offset (fixed per thread)
    const int kb  = tid >> 8;          // x: k4 base (0 or 1); k4 = kb + 2*it
    const int nodeA = base + mA;
    const bool okA  = nodeA < N;

    float4 wv, xv[4];
    wv = W4[wO * 32 + wK4];
#pragma unroll
    for (int it = 0; it < 4; ++it) {
        xv[it] = make_float4(0.f, 0.f, 0.f, 0.f);
        if (okA) xv[it] = x4p[(size_t)nodeA * 32 + kb + 2 * it];
    }

    float4 b4 = ((const float4*)b1)[tx];
    float4 acc[8];
#pragma unroll
    for (int mm = 0; mm < 8; ++mm) acc[mm] = b4;

    for (int c = 0; c < 4; ++c) {
        Wt[(4 * wK4 + 0) * 64 + wO] = wv.x;
        Wt[(4 * wK4 + 1) * 64 + wO] = wv.y;
        Wt[(4 * wK4 + 2) * 64 + wO] = wv.z;
        Wt[(4 * wK4 + 3) * 64 + wO] = wv.w;
#pragma unroll
        for (int it = 0; it < 4; ++it) {
            const int k4 = kb + 2 * it;
            xT[(4 * k4 + 0) * 256 + mA] = xv[it].x;
            xT[(4 * k4 + 1) * 256 + mA] = xv[it].y;
            xT[(4 * k4 + 2) * 256 + mA] = xv[it].z;
            xT[(4 * k4 + 3) * 256 + mA] = xv[it].w;
        }
        __syncthreads();

        if (c < 3) {
            const int ko = (c + 1) * 8;
            wv = W4[wO * 32 + ko + wK4];
#pragma unroll
            for (int it = 0; it < 4; ++it)
                if (okA) xv[it] = x4p[(size_t)nodeA * 32 + ko + kb + 2 * it];
        }

#pragma unroll 4
        for (int k = 0; k < 32; ++k) {
            const float4 w4 = *(const float4*)&Wt[k * 64 + 4 * tx];
            const float4 xa = *(const float4*)&xT[k * 256 + 8 * ty];
            const float4 xb = *(const float4*)&xT[k * 256 + 8 * ty + 4];
            GEMM_BODY(w4, xa, xb)
        }
        if (c < 3) __syncthreads();
    }

#pragma unroll
    for (int mm = 0; mm < 8; ++mm) {
        float4 r = acc[mm];
        r.x = fmaxf(r.x, 0.f); r.y = fmaxf(r.y, 0.f);
        r.z = fmaxf(r.z, 0.f); r.w = fmaxf(r.w, 0.f);
        float s = fmaf(r.x, r.x, fmaf(r.y, r.y, fmaf(r.z, r.z, r.w * r.w)));
        s = dpp_addf<0xB1>(s);
        s = dpp_addf<0x4E>(s);
        s = dpp_addf<0x141>(s);
        s = dpp_addf<0x140>(s);
        const float nn  = sqrtf(s) + 1e-12f;
        const float inv = 1.f / nn;
        int node = base + 8 * ty + mm;
        if (node < N) {
            U2H pk;
            pk.h[0] = mkh2(r.x * inv, r.y * inv);
            pk.h[1] = mkh2(r.z * inv, r.w * inv);
            *(uint2*)&xn[(size_t)node * 64 + 4 * tx] = pk.u;
            if (tx == mm) nrm[node] = nn;
        }
    }
}

// BURST-GATHER agnn (round-7, unchanged): 4 nodes/wave (16 lanes); 2 groups
// x 8 lanes take contiguous halves; per iteration a group loads 8 rows +
// 8 nrms as one burst, then computes 8 masked edge bodies.
__global__ __launch_bounds__(256, 6) void agnn_layer(const uint4* __restrict__ xn4,
                                                     const float* __restrict__ nrm,
                                                     const int4* __restrict__ meta,
                                                     const int* __restrict__ col,
                                                     uint4* __restrict__ xo4,
                                                     float* __restrict__ nrmo,
                                                     int N) {
    const int tid  = threadIdx.x;
    const int lane = tid & 63;
    const int g    = (lane >> 3) & 1;
    const int sub  = lane & 7;
    const int slot = blockIdx.x * 16 + (tid >> 4);
    if (slot >= N) return;

    const int4 m0 = meta[slot];
    const int i  = m0.x;
    const int p0 = m0.y, p1 = m0.z;

    U4H hi_;
    hi_.u = xn4[(unsigned)i * 8u + sub];
    {
        const _Float16 L2E = (_Float16)1.4426950408889634f;
        h2 l2 = {L2E, L2E};
#pragma unroll
        for (int c = 0; c < 4; ++c) hi_.h[c] *= l2;   // p = exp2(dot)
    }

    const int mid = p0 + ((p1 - p0 + 1) >> 1);
    int       t   = g ? mid : p0;
    const int e_  = g ? p1  : mid;

    float den = 0.f;
    U4H acc;
    acc.h[0] = mkh2(0.f, 0.f); acc.h[1] = mkh2(0.f, 0.f);
    acc.h[2] = mkh2(0.f, 0.f); acc.h[3] = mkh2(0.f, 0.f);

    for (; t < e_; t += 8) {
        const int nb = e_ - t;
        int   jj[8];
        uint4 v[8];
        float nm[8];

#pragma unroll
        for (int k = 0; k < 8; ++k) {
            int e = t + k;
            e = (e < e_) ? e : (e_ - 1);
            jj[k] = col[e];
        }
#pragma unroll
        for (int k = 0; k < 8; ++k) v[k] = xn4[(unsigned)jj[k] * 8u + sub];
#pragma unroll
        for (int k = 0; k < 8; ++k) nm[k] = nrm[jj[k]];

#pragma unroll
        for (int k = 0; k < 8; ++k) {
            U4H xa; xa.u = v[k];
            float sa = __builtin_amdgcn_fdot2(hi_.h[0], xa.h[0], 0.f, false);
            sa = __builtin_amdgcn_fdot2(hi_.h[1], xa.h[1], sa, false);
            float sb = __builtin_amdgcn_fdot2(hi_.h[2], xa.h[2], 0.f, false);
            sb = __builtin_amdgcn_fdot2(hi_.h[3], xa.h[3], sb, false);
            float s = sa + sb;
            s = dpp_addf<0xB1>(s);
            s = dpp_addf<0x4E>(s);
            s = dpp_addf<0x141>(s);
            const float p = (k < nb) ? exp2f(s) : 0.f;
            den += p;
            const _Float16 wh = (_Float16)(p * nm[k]);
            h2 w2 = {wh, wh};
            acc.h[0] += w2 * xa.h[0];
            acc.h[1] += w2 * xa.h[1];
            acc.h[2] += w2 * xa.h[2];
            acc.h[3] += w2 * xa.h[3];
        }
    }

    den = dpp_addf<0x140>(den);
#pragma unroll
    for (int c = 0; c < 4; ++c) {
        UHI a; a.h = acc.h[c];
        UHI b; b.u = (unsigned)__shfl_xor((int)a.u, 8, 64);
        acc.h[c] = a.h + b.h;
    }

    const float id = 1.f / fmaxf(den, 1e-12f);
    float o[8];
#pragma unroll
    for (int c = 0; c < 4; ++c) {
        o[2 * c]     = fmaxf((float)acc.h[c].x * id, 0.f);
        o[2 * c + 1] = fmaxf((float)acc.h[c].y * id, 0.f);
    }

    float s2 = 0.f;
#pragma unroll
    for (int c = 0; c < 8; ++c) s2 = fmaf(o[c], o[c], s2);
    s2 = dpp_addf<0xB1>(s2);
    s2 = dpp_addf<0x4E>(s2);
    s2 = dpp_addf<0x141>(s2);
    const float nn  = sqrtf(s2) + 1e-12f;
    const float inv = 1.f / nn;

    if (g == 0) {
        U4H ov;
        ov.h[0] = mkh2(o[0] * inv, o[1] * inv);
        ov.h[1] = mkh2(o[2] * inv, o[3] * inv);
        ov.h[2] = mkh2(o[4] * inv, o[5] * inv);
        ov.h[3] = mkh2(o[6] * inv, o[7] * inv);
        xo4[(unsigned)i * 8u + sub] = ov.u;
        if (sub == 0) nrmo[i] = nn;
    }
}

// out[i,:64] = (xn[i]*nrm[i]) @ W2^T + b2   (f32 out)
// 512 threads, tile 256 nodes x 64 outs, thread = 8 nodes x 4 outs.
// K=64 in two 32-chunks with register prefetch.
__global__ __launch_bounds__(512) void gemm2(const unsigned short* __restrict__ xn,
                                             const float* __restrict__ nrm,
                                             const float* __restrict__ W2,
                                             const float* __restrict__ b2,
                                             float* __restrict__ out,
                                             int N) {
    __shared__ __align__(16) float Wt[32 * 64];    // 8 KiB
    __shared__ __align__(16) float xT[32 * 256];   // 32 KiB
    const int tid  = threadIdx.x;
    const int tx   = tid & 15;
    const int ty   = tid >> 4;
    const int base = blockIdx.x * 256;

    const float4* W4 = (const float4*)W2;
    const uint2*  x2 = (const uint2*)xn;

    const int wO  = tid & 63;
    const int wK4 = tid >> 6;          // [0,8)
    const int mA  = tid & 255;
    const int kb  = tid >> 8;          // 0 or 1
    const int nodeA = base + mA;
    const bool okA  = nodeA < N;

    float nnA = 0.f;
    if (okA) nnA = nrm[nodeA];

    float4 wv;
    U2H xv[4];
    wv = W4[wO * 16 + wK4];
#pragma unroll
    for (int it = 0; it < 4; ++it) {
        xv[it].u = make_uint2(0u, 0u);
        if (okA) xv[it].u = x2[(size_t)nodeA * 16 + kb + 2 * it];
    }

    float4 b4 = ((const float4*)b2)[tx];
    float4 acc[8];
#pragma unroll
    for (int mm = 0; mm < 8; ++mm) acc[mm] = b4;

    for (int c = 0; c < 2; ++c) {
        Wt[(4 * wK4 + 0) * 64 + wO] = wv.x;
        Wt[(4 * wK4 + 1) * 64 + wO] = wv.y;
        Wt[(4 * wK4 + 2) * 64 + wO] = wv.z;
        Wt[(4 * wK4 + 3) * 64 + wO] = wv.w;
#pragma unroll
        for (int it = 0; it < 4; ++it) {
            const int k4 = kb + 2 * it;
            xT[(4 * k4 + 0) * 256 + mA] = (float)xv[it].h[0].x * nnA;
            xT[(4 * k4 + 1) * 256 + mA] = (float)xv[it].h[0].y * nnA;
            xT[(4 * k4 + 2) * 256 + mA] = (float)xv[it].h[1].x * nnA;
            xT[(4 * k4 + 3) * 256 + mA] = (float)xv[it].h[1].y * nnA;
        }
        __syncthreads();

        if (c == 0) {
            wv = W4[wO * 16 + 8 + wK4];
#pragma unroll
            for (int it = 0; it < 4; ++it)
                if (okA) xv[it].u = x2[(size_t)nodeA * 16 + 8 + kb + 2 * it];
        }

#pragma unroll 4
        for (int k = 0; k < 32; ++k) {
            const float4 w4 = *(const float4*)&Wt[k * 64 + 4 * tx];
            const float4 xa = *(const float4*)&xT[k * 256 + 8 * ty];
            const float4 xb = *(const float4*)&xT[k * 256 + 8 * ty + 4];
            GEMM_BODY(w4, xa, xb)
        }
        if (c == 0) __syncthreads();
    }

#pragma unroll
    for (int mm = 0; mm < 8; ++mm) {
        int node = base + 8 * ty + mm;
        if (node < N) *(float4*)&out[(size_t)node * 64 + 4 * tx] = acc[mm];
    }
}

extern "C" void kernel_launch(void* const* d_in, const int* in_sizes, int n_in,
                              void* d_out, int out_size, void* d_ws, size_t ws_size,
                              hipStream_t stream) {
    const float* x   = (const float*)d_in[0];
    const int*   row = (const int*)d_in[1];
    const int*   col = (const int*)d_in[2];
    const float* W1  = (const float*)d_in[3];
    const float* b1  = (const float*)d_in[4];
    const float* W2  = (const float*)d_in[5];
    const float* b2  = (const float*)d_in[6];
    float* out = (float*)d_out;

    const int N = in_sizes[0] / 128;
    const int E = in_sizes[1];

    char* ws = (char*)d_ws;
    size_t off = 0;
    unsigned short* ha = (unsigned short*)(ws + off); off += (size_t)N * 64 * 2;
    unsigned short* hb = (unsigned short*)(ws + off); off += (size_t)N * 64 * 2;
    float* na_  = (float*)(ws + off); off += (size_t)N * sizeof(float);
    float* nb_  = (float*)(ws + off); off += (size_t)N * sizeof(float);
    int*   ptr  = (int*)  (ws + off); off += (size_t)(N + 1) * sizeof(int);
    off = (off + 15) & ~(size_t)15;
    int4*  meta = (int4*) (ws + off); off += (size_t)N * sizeof(int4);
    (void)ws_size; (void)n_in; (void)out_size;

    build_rowptr_scan<<<(E + 255) / 256, 256, 0, stream>>>(row, ptr, N, E);

    build_perm_seg<<<(N + PSEG - 1) / PSEG, 1024, 0, stream>>>(ptr, meta, N);

    const int nbG = (N + 255) / 256;
    gemm1_relu<<<nbG, 512, 0, stream>>>(x, W1, b1, ha, na_, N);

    const int nb16 = (N + 15) / 16;
    unsigned short* hc = ha; unsigned short* hn = hb;
    float* nc = na_; float* nn = nb_;
    for (int l = 0; l < 4; ++l) {
        agnn_layer<<<nb16, 256, 0, stream>>>((const uint4*)hc, nc, meta, col,
                                             (uint4*)hn, nn, N);
        unsigned short* t = hc; hc = hn; hn = t;
        float* tf = nc; nc = nn; nn = tf;
    }

    gemm2<<<nbG, 512, 0, stream>>>(hc, nc, W2, b2, out, N);
}

// Round 9
// 296.841 us; speedup vs baseline: 1.0078x; 1.0078x over previous
//
#include <hip/hip_runtime.h>

// ---------------------------------------------------------------------------
// AGNN: h = relu(x@W1^T+b1); 4x [ h = relu(agnn(h)) ]; out = h@W2^T+b2
// N=100000, E=1600000, IN=128, HID=OUT=64, float32 in/out.
// Between layers: xn = h/(||h||+eps) stored FP16 (128 B/row) + nrm f32.
//   p = exp2( dot(xn_i * log2e, xn_j) );  out_i = sum p * nrm_j * xn_j / sum p
// Round 9: gemm GRID-STARVATION fix. r8's 256-tile gave 391 blocks
//   (1.5/CU, Occ 15%, VALU 30%, 47.9 us). Revert density, maximize blocks:
//   64-node x 64-out tile, 256 threads, 4x4/thread -> 1563 blocks (6.1/CU),
//   16 KB LDS (gemm1, chunked K + reg prefetch) / 32 KB (gemm2, full K).
// agnn: r7 burst-gather, at the HBM random-sector wall (~40 us/layer,
//   97 MB random 64B sectors; 4 structural rewrites all 40+-1). Unchanged.
// rowptr O(E) scan + 1024-seg counting sort (meta int4) unchanged.
// ---------------------------------------------------------------------------

typedef _Float16 h2 __attribute__((ext_vector_type(2)));

union U4H { uint4 u; h2 h[4]; };
union U2H { uint2 u; h2 h[2]; };
union UHI { unsigned u; h2 h; };
union UF  { unsigned u; float f; int i; };

#define DEV_INLINE __device__ __forceinline__

DEV_INLINE h2 mkh2(float a, float b) {
    h2 r; r.x = (_Float16)a; r.y = (_Float16)b; return r;
}

// x + dpp_perm(x): 0xB1 quad_perm xor1, 0x4E quad_perm xor2,
// 0x141 row_half_mirror (i^7 == xor4 after quads uniform),
// 0x140 row_mirror (i^15 == xor8 after 8-groups uniform).
template <int CTRL>
DEV_INLINE float dpp_addf(float x) {
    UF a, b;
    a.f = x;
    b.i = __builtin_amdgcn_update_dpp(0, a.i, CTRL, 0xF, 0xF, true);
    return x + b.f;
}

// ptr[i] = lower_bound(row, i). Thread e covers i in (row[e-1], row[e]].
__global__ __launch_bounds__(256) void build_rowptr_scan(const int* __restrict__ row,
                                                         int* __restrict__ ptr,
                                                         int N, int E) {
    int e = blockIdx.x * blockDim.x + threadIdx.x;
    if (e >= E) return;
    const int r1 = row[e];
    const int r0 = (e == 0) ? -1 : row[e - 1];
    for (int i = r0 + 1; i <= r1; ++i) ptr[i] = e;
    if (e == E - 1) {
        for (int i = r1 + 1; i <= N; ++i) ptr[i] = E;
    }
}

// Segment-local counting sort by degree; emits meta[pos] = (nid, p0, p1, 0).
#define PSEG 1024
__global__ __launch_bounds__(1024) void build_perm_seg(const int* __restrict__ ptr,
                                                       int4* __restrict__ meta,
                                                       int N) {
    __shared__ int hist[256];
    __shared__ int tmp[256];
    const int t    = threadIdx.x;
    const int base = blockIdx.x * PSEG;
    const int end  = (base + PSEG < N) ? base + PSEG : N;
    const int cnt  = end - base;

    if (t < 256) hist[t] = 0;
    __syncthreads();

    int d = -1, p0v = 0, p1v = 0;
    if (t < cnt) {
        p0v = ptr[base + t];
        p1v = ptr[base + t + 1];
        d = p1v - p0v;
        if (d > 255) d = 255;
        atomicAdd(&hist[d], 1);
    }
    __syncthreads();

    int h0 = (t < 256) ? hist[t] : 0;
    int* src = hist; int* dst = tmp;
    for (int off = 1; off < 256; off <<= 1) {
        if (t < 256) dst[t] = src[t] + (t >= off ? src[t - off] : 0);
        __syncthreads();
        int* tt = src; src = dst; dst = tt;
    }
    if (t < 256) src[t] -= h0;
    __syncthreads();

    if (t < cnt) {
        int pos = base + atomicAdd(&src[d], 1);
        meta[pos] = make_int4(base + t, p0v, p1v, 0);
    }
}

#define GEMM_BODY4(w4, xv)                                      \
    acc[0].x = fmaf(xv.x, w4.x, acc[0].x);                      \
    acc[0].y = fmaf(xv.x, w4.y, acc[0].y);                      \
    acc[0].z = fmaf(xv.x, w4.z, acc[0].z);                      \
    acc[0].w = fmaf(xv.x, w4.w, acc[0].w);                      \
    acc[1].x = fmaf(xv.y, w4.x, acc[1].x);                      \
    acc[1].y = fmaf(xv.y, w4.y, acc[1].y);                      \
    acc[1].z = fmaf(xv.y, w4.z, acc[1].z);                      \
    acc[1].w = fmaf(xv.y, w4.w, acc[1].w);                      \
    acc[2].x = fmaf(xv.z, w4.x, acc[2].x);                      \
    acc[2].y = fmaf(xv.z, w4.y, acc[2].y);                      \
    acc[2].z = fmaf(xv.z, w4.z, acc[2].z);                      \
    acc[2].w = fmaf(xv.z, w4.w, acc[2].w);                      \
    acc[3].x = fmaf(xv.w, w4.x, acc[3].x);                      \
    acc[3].y = fmaf(xv.w, w4.y, acc[3].y);                      \
    acc[3].z = fmaf(xv.w, w4.z, acc[3].z);                      \
    acc[3].w = fmaf(xv.w, w4.w, acc[3].w);

// r = relu(x[i,:128]@W1^T + b1); xn[i]=f16(r/(||r||+eps)); nrm[i]=||r||+eps
// 256 threads, tile 64 nodes x 64 outs, thread = 4 nodes x 4 outs.
// K in four 32-chunks with register prefetch. 1563 blocks -> 6.1/CU.
__global__ __launch_bounds__(256) void gemm1_relu(const float* __restrict__ x,
                                                  const float* __restrict__ W1,
                                                  const float* __restrict__ b1,
                                                  unsigned short* __restrict__ xn,
                                                  float* __restrict__ nrm,
                                                  int N) {
    __shared__ __align__(16) float Wt[32 * 64];   // 8 KiB
    __shared__ __align__(16) float xT[32 * 64];   // 8 KiB
    const int tid  = threadIdx.x;
    const int tx   = tid & 15;    // 4 outs at 4*tx
    const int ty   = tid >> 4;    // 4 nodes at 4*ty, ty in [0,16)
    const int base = blockIdx.x * 64;

    const float4* W4  = (const float4*)W1;
    const float4* x4p = (const float4*)x;

    // staging: thread covers (o=wO, k4=wK4) and (o=wO, k4=wK4+4) for W,
    //          (node=wO, k4=wK4) and (node=wO, k4=wK4+4) for x.
    const int wO  = tid & 63;
    const int wK4 = tid >> 6;          // [0,4)
    const int nodeA = base + wO;
    const bool okA  = nodeA < N;

    float4 wv0, wv1, xv0, xv1;
    wv0 = W4[wO * 32 + wK4];
    wv1 = W4[wO * 32 + 4 + wK4];
    xv0 = make_float4(0.f, 0.f, 0.f, 0.f);
    xv1 = xv0;
    if (okA) {
        xv0 = x4p[(size_t)nodeA * 32 + wK4];
        xv1 = x4p[(size_t)nodeA * 32 + 4 + wK4];
    }

    float4 b4 = ((const float4*)b1)[tx];
    float4 acc[4];
    acc[0] = b4; acc[1] = b4; acc[2] = b4; acc[3] = b4;

    for (int c = 0; c < 4; ++c) {
        Wt[(4 * wK4 + 0) * 64 + wO] = wv0.x;
        Wt[(4 * wK4 + 1) * 64 + wO] = wv0.y;
        Wt[(4 * wK4 + 2) * 64 + wO] = wv0.z;
        Wt[(4 * wK4 + 3) * 64 + wO] = wv0.w;
        Wt[(4 * (wK4 + 4) + 0) * 64 + wO] = wv1.x;
        Wt[(4 * (wK4 + 4) + 1) * 64 + wO] = wv1.y;
        Wt[(4 * (wK4 + 4) + 2) * 64 + wO] = wv1.z;
        Wt[(4 * (wK4 + 4) + 3) * 64 + wO] = wv1.w;
        xT[(4 * wK4 + 0) * 64 + wO] = xv0.x;
        xT[(4 * wK4 + 1) * 64 + wO] = xv0.y;
        xT[(4 * wK4 + 2) * 64 + wO] = xv0.z;
        xT[(4 * wK4 + 3) * 64 + wO] = xv0.w;
        xT[(4 * (wK4 + 4) + 0) * 64 + wO] = xv1.x;
        xT[(4 * (wK4 + 4) + 1) * 64 + wO] = xv1.y;
        xT[(4 * (wK4 + 4) + 2) * 64 + wO] = xv1.z;
        xT[(4 * (wK4 + 4) + 3) * 64 + wO] = xv1.w;
        __syncthreads();

        if (c < 3) {
            const int ko = (c + 1) * 8;
            wv0 = W4[wO * 32 + ko + wK4];
            wv1 = W4[wO * 32 + ko + 4 + wK4];
            if (okA) {
                xv0 = x4p[(size_t)nodeA * 32 + ko + wK4];
                xv1 = x4p[(size_t)nodeA * 32 + ko + 4 + wK4];
            }
        }

#pragma unroll 4
        for (int k = 0; k < 32; ++k) {
            const float4 w4 = *(const float4*)&Wt[k * 64 + 4 * tx];
            const float4 xv = *(const float4*)&xT[k * 64 + 4 * ty];
            GEMM_BODY4(w4, xv)
        }
        if (c < 3) __syncthreads();
    }

#pragma unroll
    for (int mm = 0; mm < 4; ++mm) {
        float4 r = acc[mm];
        r.x = fmaxf(r.x, 0.f); r.y = fmaxf(r.y, 0.f);
        r.z = fmaxf(r.z, 0.f); r.w = fmaxf(r.w, 0.f);
        float s = fmaf(r.x, r.x, fmaf(r.y, r.y, fmaf(r.z, r.z, r.w * r.w)));
        s = dpp_addf<0xB1>(s);
        s = dpp_addf<0x4E>(s);
        s = dpp_addf<0x141>(s);
        s = dpp_addf<0x140>(s);
        const float nn  = sqrtf(s) + 1e-12f;
        const float inv = 1.f / nn;
        int node = base + 4 * ty + mm;
        if (node < N) {
            U2H pk;
            pk.h[0] = mkh2(r.x * inv, r.y * inv);
            pk.h[1] = mkh2(r.z * inv, r.w * inv);
            *(uint2*)&xn[(size_t)node * 64 + 4 * tx] = pk.u;
            if (tx == mm) nrm[node] = nn;
        }
    }
}

// BURST-GATHER agnn (round-7, unchanged): 4 nodes/wave (16 lanes); 2 groups
// x 8 lanes take contiguous halves; per iteration a group loads 8 rows +
// 8 nrms as one burst, then computes 8 masked edge bodies.
__global__ __launch_bounds__(256, 6) void agnn_layer(const uint4* __restrict__ xn4,
                                                     const float* __restrict__ nrm,
                                                     const int4* __restrict__ meta,
                                                     const int* __restrict__ col,
                                                     uint4* __restrict__ xo4,
                                                     float* __restrict__ nrmo,
                                                     int N) {
    const int tid  = threadIdx.x;
    const int lane = tid & 63;
    const int g    = (lane >> 3) & 1;
    const int sub  = lane & 7;
    const int slot = blockIdx.x * 16 + (tid >> 4);
    if (slot >= N) return;

    const int4 m0 = meta[slot];
    const int i  = m0.x;
    const int p0 = m0.y, p1 = m0.z;

    U4H hi_;
    hi_.u = xn4[(unsigned)i * 8u + sub];
    {
        const _Float16 L2E = (_Float16)1.4426950408889634f;
        h2 l2 = {L2E, L2E};
#pragma unroll
        for (int c = 0; c < 4; ++c) hi_.h[c] *= l2;   // p = exp2(dot)
    }

    const int mid = p0 + ((p1 - p0 + 1) >> 1);
    int       t   = g ? mid : p0;
    const int e_  = g ? p1  : mid;

    float den = 0.f;
    U4H acc;
    acc.h[0] = mkh2(0.f, 0.f); acc.h[1] = mkh2(0.f, 0.f);
    acc.h[2] = mkh2(0.f, 0.f); acc.h[3] = mkh2(0.f, 0.f);

    for (; t < e_; t += 8) {
        const int nb = e_ - t;
        int   jj[8];
        uint4 v[8];
        float nm[8];

#pragma unroll
        for (int k = 0; k < 8; ++k) {
            int e = t + k;
            e = (e < e_) ? e : (e_ - 1);
            jj[k] = col[e];
        }
#pragma unroll
        for (int k = 0; k < 8; ++k) v[k] = xn4[(unsigned)jj[k] * 8u + sub];
#pragma unroll
        for (int k = 0; k < 8; ++k) nm[k] = nrm[jj[k]];

#pragma unroll
        for (int k = 0; k < 8; ++k) {
            U4H xa; xa.u = v[k];
            float sa = __builtin_amdgcn_fdot2(hi_.h[0], xa.h[0], 0.f, false);
            sa = __builtin_amdgcn_fdot2(hi_.h[1], xa.h[1], sa, false);
            float sb = __builtin_amdgcn_fdot2(hi_.h[2], xa.h[2], 0.f, false);
            sb = __builtin_amdgcn_fdot2(hi_.h[3], xa.h[3], sb, false);
            float s = sa + sb;
            s = dpp_addf<0xB1>(s);
            s = dpp_addf<0x4E>(s);
            s = dpp_addf<0x141>(s);
            const float p = (k < nb) ? exp2f(s) : 0.f;
            den += p;
            const _Float16 wh = (_Float16)(p * nm[k]);
            h2 w2 = {wh, wh};
            acc.h[0] += w2 * xa.h[0];
            acc.h[1] += w2 * xa.h[1];
            acc.h[2] += w2 * xa.h[2];
            acc.h[3] += w2 * xa.h[3];
        }
    }

    den = dpp_addf<0x140>(den);
#pragma unroll
    for (int c = 0; c < 4; ++c) {
        UHI a; a.h = acc.h[c];
        UHI b; b.u = (unsigned)__shfl_xor((int)a.u, 8, 64);
        acc.h[c] = a.h + b.h;
    }

    const float id = 1.f / fmaxf(den, 1e-12f);
    float o[8];
#pragma unroll
    for (int c = 0; c < 4; ++c) {
        o[2 * c]     = fmaxf((float)acc.h[c].x * id, 0.f);
        o[2 * c + 1] = fmaxf((float)acc.h[c].y * id, 0.f);
    }

    float s2 = 0.f;
#pragma unroll
    for (int c = 0; c < 8; ++c) s2 = fmaf(o[c], o[c], s2);
    s2 = dpp_addf<0xB1>(s2);
    s2 = dpp_addf<0x4E>(s2);
    s2 = dpp_addf<0x141>(s2);
    const float nn  = sqrtf(s2) + 1e-12f;
    const float inv = 1.f / nn;

    if (g == 0) {
        U4H ov;
        ov.h[0] = mkh2(o[0] * inv, o[1] * inv);
        ov.h[1] = mkh2(o[2] * inv, o[3] * inv);
        ov.h[2] = mkh2(o[4] * inv, o[5] * inv);
        ov.h[3] = mkh2(o[6] * inv, o[7] * inv);
        xo4[(unsigned)i * 8u + sub] = ov.u;
        if (sub == 0) nrmo[i] = nn;
    }
}

// out[i,:64] = (xn[i]*nrm[i]) @ W2^T + b2   (f32 out)
// 256 threads, tile 64 nodes x 64 outs, thread = 4 nodes x 4 outs.
// Full K=64 staged once (32 KB LDS), 1563 blocks.
__global__ __launch_bounds__(256) void gemm2(const unsigned short* __restrict__ xn,
                                             const float* __restrict__ nrm,
                                             const float* __restrict__ W2,
                                             const float* __restrict__ b2,
                                             float* __restrict__ out,
                                             int N) {
    __shared__ __align__(16) float Wt[64 * 64];   // 16 KiB
    __shared__ __align__(16) float xT[64 * 64];   // 16 KiB
    const int tid  = threadIdx.x;
    const int tx   = tid & 15;
    const int ty   = tid >> 4;    // [0,16)
    const int base = blockIdx.x * 64;

    {
        const float4* W4 = (const float4*)W2;
#pragma unroll
        for (int it = 0; it < 4; ++it) {
            int idx = tid + it * 256;              // 1024 total
            int o = idx & 63, k4 = idx >> 6;       // k4 in [0,16)
            float4 v = W4[o * 16 + k4];
            Wt[(4 * k4 + 0) * 64 + o] = v.x;
            Wt[(4 * k4 + 1) * 64 + o] = v.y;
            Wt[(4 * k4 + 2) * 64 + o] = v.z;
            Wt[(4 * k4 + 3) * 64 + o] = v.w;
        }
        const uint2* x2 = (const uint2*)xn;
#pragma unroll
        for (int it = 0; it < 4; ++it) {
            int idx = tid + it * 256;              // 1024 total
            int mm = idx & 63, k4 = idx >> 6;      // k4 in [0,16)
            int node = base + mm;
            U2H v; v.u = make_uint2(0u, 0u);
            float nn = 0.f;
            if (node < N) { v.u = x2[(size_t)node * 16 + k4]; nn = nrm[node]; }
            xT[(4 * k4 + 0) * 64 + mm] = (float)v.h[0].x * nn;
            xT[(4 * k4 + 1) * 64 + mm] = (float)v.h[0].y * nn;
            xT[(4 * k4 + 2) * 64 + mm] = (float)v.h[1].x * nn;
            xT[(4 * k4 + 3) * 64 + mm] = (float)v.h[1].y * nn;
        }
    }
    __syncthreads();

    float4 b4 = ((const float4*)b2)[tx];
    float4 acc[4];
    acc[0] = b4; acc[1] = b4; acc[2] = b4; acc[3] = b4;

#pragma unroll 4
    for (int k = 0; k < 64; ++k) {
        const float4 w4 = *(const float4*)&Wt[k * 64 + 4 * tx];
        const float4 xv = *(const float4*)&xT[k * 64 + 4 * ty];
        GEMM_BODY4(w4, xv)
    }

#pragma unroll
    for (int mm = 0; mm < 4; ++mm) {
        int node = base + 4 * ty + mm;
        if (node < N) *(float4*)&out[(size_t)node * 64 + 4 * tx] = acc[mm];
    }
}

extern "C" void kernel_launch(void* const* d_in, const int* in_sizes, int n_in,
                              void* d_out, int out_size, void* d_ws, size_t ws_size,
                              hipStream_t stream) {
    const float* x   = (const float*)d_in[0];
    const int*   row = (const int*)d_in[1];
    const int*   col = (const int*)d_in[2];
    const float* W1  = (const float*)d_in[3];
    const float* b1  = (const float*)d_in[4];
    const float* W2  = (const float*)d_in[5];
    const float* b2  = (const float*)d_in[6];
    float* out = (float*)d_out;

    const int N = in_sizes[0] / 128;
    const int E = in_sizes[1];

    char* ws = (char*)d_ws;
    size_t off = 0;
    unsigned short* ha = (unsigned short*)(ws + off); off += (size_t)N * 64 * 2;
    unsigned short* hb = (unsigned short*)(ws + off); off += (size_t)N * 64 * 2;
    float* na_  = (float*)(ws + off); off += (size_t)N * sizeof(float);
    float* nb_  = (float*)(ws + off); off += (size_t)N * sizeof(float);
    int*   ptr  = (int*)  (ws + off); off += (size_t)(N + 1) * sizeof(int);
    off = (off + 15) & ~(size_t)15;
    int4*  meta = (int4*) (ws + off); off += (size_t)N * sizeof(int4);
    (void)ws_size; (void)n_in; (void)out_size;

    build_rowptr_scan<<<(E + 255) / 256, 256, 0, stream>>>(row, ptr, N, E);

    build_perm_seg<<<(N + PSEG - 1) / PSEG, 1024, 0, stream>>>(ptr, meta, N);

    const int nbG = (N + 63) / 64;
    gemm1_relu<<<nbG, 256, 0, stream>>>(x, W1, b1, ha, na_, N);

    const int nb16 = (N + 15) / 16;
    unsigned short* hc = ha; unsigned short* hn = hb;
    float* nc = na_; float* nn = nb_;
    for (int l = 0; l < 4; ++l) {
        agnn_layer<<<nb16, 256, 0, stream>>>((const uint4*)hc, nc, meta, col,
                                             (uint4*)hn, nn, N);
        unsigned short* t = hc; hc = hn; hn = t;
        float* tf = nc; nc = nn; nn = tf;
    }

    gemm2<<<nbG, 256, 0, stream>>>(hc, nc, W2, b2, out, N);
}

// Round 10
// 282.607 us; speedup vs baseline: 1.0585x; 1.0504x over previous
//
#include <hip/hip_runtime.h>

// ---------------------------------------------------------------------------
// AGNN: h = relu(x@W1^T+b1); 4x [ h = relu(agnn(h)) ]; out = h@W2^T+b2
// N=100000, E=1600000, IN=128, HID=OUT=64, float32 in/out.
// Between layers: xn = h/(||h||+eps) stored FP16 (128 B/row) + nrm f32.
//   p = exp2( dot(xn_i * log2e, xn_j) );  out_i = sum p * nrm_j * xn_j / sum p
// Round 10: KERNEL FUSION (r8/r9: gemm tuning is total-neutral; overhead is
//   launches + producer->consumer round-trips).
//   - gemm2 fused into agnn layer 4: quarter holds full o[64] in regs ->
//     oLDS + W2^T in LDS (stride 68, bank-friendly), 64 k-steps x 4 FMA
//     per lane. 5.2 us of FLOPs hidden under agnn stalls; kills the
//     standalone gemm2 kernel, its launch gap, and the 12.8 MB xn write +
//     re-read. Output now from f32 o (skips f16 rounding) -> absmax <=.
//   - rowptr fused into sort via per-thread binary search (ptr_s in LDS);
//     kills the rowptr kernel + global ptr array.
//   Launches 8 -> 6. agnn body (r7 burst, at random-gather wall) unchanged.
// ---------------------------------------------------------------------------

typedef _Float16 h2 __attribute__((ext_vector_type(2)));

union U4H { uint4 u; h2 h[4]; };
union U2H { uint2 u; h2 h[2]; };
union UHI { unsigned u; h2 h; };
union UF  { unsigned u; float f; int i; };

#define DEV_INLINE __device__ __forceinline__

DEV_INLINE h2 mkh2(float a, float b) {
    h2 r; r.x = (_Float16)a; r.y = (_Float16)b; return r;
}

// x + dpp_perm(x): 0xB1 quad_perm xor1, 0x4E quad_perm xor2,
// 0x141 row_half_mirror (i^7 == xor4 after quads uniform),
// 0x140 row_mirror (i^15 == xor8 after 8-groups uniform).
template <int CTRL>
DEV_INLINE float dpp_addf(float x) {
    UF a, b;
    a.f = x;
    b.i = __builtin_amdgcn_update_dpp(0, a.i, CTRL, 0xF, 0xF, true);
    return x + b.f;
}

// Fused rowptr(binary search) + segment-local degree counting sort.
// One 1024-thread block per 1024-node segment; emits meta = (nid,p0,p1,0).
#define PSEG 1024
__global__ __launch_bounds__(1024) void build_meta_sort(const int* __restrict__ row,
                                                        int4* __restrict__ meta,
                                                        int N, int E) {
    __shared__ int ptr_s[PSEG + 1];
    __shared__ int hist[256];
    __shared__ int tmp[256];
    const int t    = threadIdx.x;
    const int base = blockIdx.x * PSEG;
    const int end  = (base + PSEG < N) ? base + PSEG : N;
    const int cnt  = end - base;

    if (t < cnt) {
        const int target = base + t;
        int lo = 0, hi = E;
        while (lo < hi) {
            int mid = (lo + hi) >> 1;
            if (row[mid] < target) lo = mid + 1; else hi = mid;
        }
        ptr_s[t] = lo;
    }
    if (t == 0) {
        const int target = end;
        int lo = 0, hi = E;
        while (lo < hi) {
            int mid = (lo + hi) >> 1;
            if (row[mid] < target) lo = mid + 1; else hi = mid;
        }
        ptr_s[cnt] = lo;
    }
    if (t < 256) hist[t] = 0;
    __syncthreads();

    int d = -1, p0v = 0, p1v = 0;
    if (t < cnt) {
        p0v = ptr_s[t];
        p1v = ptr_s[t + 1];
        d = p1v - p0v;
        if (d > 255) d = 255;
        atomicAdd(&hist[d], 1);
    }
    __syncthreads();

    int h0 = (t < 256) ? hist[t] : 0;
    int* src = hist; int* dst = tmp;
    for (int off = 1; off < 256; off <<= 1) {
        if (t < 256) dst[t] = src[t] + (t >= off ? src[t - off] : 0);
        __syncthreads();
        int* tt = src; src = dst; dst = tt;
    }
    if (t < 256) src[t] -= h0;
    __syncthreads();

    if (t < cnt) {
        int pos = base + atomicAdd(&src[d], 1);
        meta[pos] = make_int4(base + t, p0v, p1v, 0);
    }
}

#define GEMM_BODY4(w4, xv)                                      \
    acc[0].x = fmaf(xv.x, w4.x, acc[0].x);                      \
    acc[0].y = fmaf(xv.x, w4.y, acc[0].y);                      \
    acc[0].z = fmaf(xv.x, w4.z, acc[0].z);                      \
    acc[0].w = fmaf(xv.x, w4.w, acc[0].w);                      \
    acc[1].x = fmaf(xv.y, w4.x, acc[1].x);                      \
    acc[1].y = fmaf(xv.y, w4.y, acc[1].y);                      \
    acc[1].z = fmaf(xv.y, w4.z, acc[1].z);                      \
    acc[1].w = fmaf(xv.y, w4.w, acc[1].w);                      \
    acc[2].x = fmaf(xv.z, w4.x, acc[2].x);                      \
    acc[2].y = fmaf(xv.z, w4.y, acc[2].y);                      \
    acc[2].z = fmaf(xv.z, w4.z, acc[2].z);                      \
    acc[2].w = fmaf(xv.z, w4.w, acc[2].w);                      \
    acc[3].x = fmaf(xv.w, w4.x, acc[3].x);                      \
    acc[3].y = fmaf(xv.w, w4.y, acc[3].y);                      \
    acc[3].z = fmaf(xv.w, w4.z, acc[3].z);                      \
    acc[3].w = fmaf(xv.w, w4.w, acc[3].w);

// r = relu(x[i,:128]@W1^T + b1); xn[i]=f16(r/(||r||+eps)); nrm[i]=||r||+eps
// 256 threads, tile 64 nodes x 64 outs, thread = 4 nodes x 4 outs.
__global__ __launch_bounds__(256) void gemm1_relu(const float* __restrict__ x,
                                                  const float* __restrict__ W1,
                                                  const float* __restrict__ b1,
                                                  unsigned short* __restrict__ xn,
                                                  float* __restrict__ nrm,
                                                  int N) {
    __shared__ __align__(16) float Wt[32 * 64];   // 8 KiB
    __shared__ __align__(16) float xT[32 * 64];   // 8 KiB
    const int tid  = threadIdx.x;
    const int tx   = tid & 15;
    const int ty   = tid >> 4;
    const int base = blockIdx.x * 64;

    const float4* W4  = (const float4*)W1;
    const float4* x4p = (const float4*)x;

    const int wO  = tid & 63;
    const int wK4 = tid >> 6;          // [0,4)
    const int nodeA = base + wO;
    const bool okA  = nodeA < N;

    float4 wv0, wv1, xv0, xv1;
    wv0 = W4[wO * 32 + wK4];
    wv1 = W4[wO * 32 + 4 + wK4];
    xv0 = make_float4(0.f, 0.f, 0.f, 0.f);
    xv1 = xv0;
    if (okA) {
        xv0 = x4p[(size_t)nodeA * 32 + wK4];
        xv1 = x4p[(size_t)nodeA * 32 + 4 + wK4];
    }

    float4 b4 = ((const float4*)b1)[tx];
    float4 acc[4];
    acc[0] = b4; acc[1] = b4; acc[2] = b4; acc[3] = b4;

    for (int c = 0; c < 4; ++c) {
        Wt[(4 * wK4 + 0) * 64 + wO] = wv0.x;
        Wt[(4 * wK4 + 1) * 64 + wO] = wv0.y;
        Wt[(4 * wK4 + 2) * 64 + wO] = wv0.z;
        Wt[(4 * wK4 + 3) * 64 + wO] = wv0.w;
        Wt[(4 * (wK4 + 4) + 0) * 64 + wO] = wv1.x;
        Wt[(4 * (wK4 + 4) + 1) * 64 + wO] = wv1.y;
        Wt[(4 * (wK4 + 4) + 2) * 64 + wO] = wv1.z;
        Wt[(4 * (wK4 + 4) + 3) * 64 + wO] = wv1.w;
        xT[(4 * wK4 + 0) * 64 + wO] = xv0.x;
        xT[(4 * wK4 + 1) * 64 + wO] = xv0.y;
        xT[(4 * wK4 + 2) * 64 + wO] = xv0.z;
        xT[(4 * wK4 + 3) * 64 + wO] = xv0.w;
        xT[(4 * (wK4 + 4) + 0) * 64 + wO] = xv1.x;
        xT[(4 * (wK4 + 4) + 1) * 64 + wO] = xv1.y;
        xT[(4 * (wK4 + 4) + 2) * 64 + wO] = xv1.z;
        xT[(4 * (wK4 + 4) + 3) * 64 + wO] = xv1.w;
        __syncthreads();

        if (c < 3) {
            const int ko = (c + 1) * 8;
            wv0 = W4[wO * 32 + ko + wK4];
            wv1 = W4[wO * 32 + ko + 4 + wK4];
            if (okA) {
                xv0 = x4p[(size_t)nodeA * 32 + ko + wK4];
                xv1 = x4p[(size_t)nodeA * 32 + ko + 4 + wK4];
            }
        }

#pragma unroll 4
        for (int k = 0; k < 32; ++k) {
            const float4 w4 = *(const float4*)&Wt[k * 64 + 4 * tx];
            const float4 xv = *(const float4*)&xT[k * 64 + 4 * ty];
            GEMM_BODY4(w4, xv)
        }
        if (c < 3) __syncthreads();
    }

#pragma unroll
    for (int mm = 0; mm < 4; ++mm) {
        float4 r = acc[mm];
        r.x = fmaxf(r.x, 0.f); r.y = fmaxf(r.y, 0.f);
        r.z = fmaxf(r.z, 0.f); r.w = fmaxf(r.w, 0.f);
        float s = fmaf(r.x, r.x, fmaf(r.y, r.y, fmaf(r.z, r.z, r.w * r.w)));
        s = dpp_addf<0xB1>(s);
        s = dpp_addf<0x4E>(s);
        s = dpp_addf<0x141>(s);
        s = dpp_addf<0x140>(s);
        const float nn  = sqrtf(s) + 1e-12f;
        const float inv = 1.f / nn;
        int node = base + 4 * ty + mm;
        if (node < N) {
            U2H pk;
            pk.h[0] = mkh2(r.x * inv, r.y * inv);
            pk.h[1] = mkh2(r.z * inv, r.w * inv);
            *(uint2*)&xn[(size_t)node * 64 + 4 * tx] = pk.u;
            if (tx == mm) nrm[node] = nn;
        }
    }
}

// Shared agnn edge-loop body (r7 burst-gather). Produces den and acc for
// the calling lane. Used by both the plain and the gemm2-fused kernels.
#define AGNN_EDGE_LOOP()                                                     \
    for (; t < e_; t += 8) {                                                 \
        const int nb = e_ - t;                                               \
        int   jj[8];                                                         \
        uint4 v[8];                                                          \
        float nm[8];                                                         \
        _Pragma("unroll")                                                    \
        for (int k = 0; k < 8; ++k) {                                        \
            int e = t + k;                                                   \
            e = (e < e_) ? e : (e_ - 1);                                     \
            jj[k] = col[e];                                                  \
        }                                                                    \
        _Pragma("unroll")                                                    \
        for (int k = 0; k < 8; ++k) v[k] = xn4[(unsigned)jj[k] * 8u + sub];  \
        _Pragma("unroll")                                                    \
        for (int k = 0; k < 8; ++k) nm[k] = nrm[jj[k]];                      \
        _Pragma("unroll")                                                    \
        for (int k = 0; k < 8; ++k) {                                        \
            U4H xa; xa.u = v[k];                                             \
            float sa = __builtin_amdgcn_fdot2(hi_.h[0], xa.h[0], 0.f, false);\
            sa = __builtin_amdgcn_fdot2(hi_.h[1], xa.h[1], sa, false);       \
            float sb = __builtin_amdgcn_fdot2(hi_.h[2], xa.h[2], 0.f, false);\
            sb = __builtin_amdgcn_fdot2(hi_.h[3], xa.h[3], sb, false);       \
            float s = sa + sb;                                               \
            s = dpp_addf<0xB1>(s);                                           \
            s = dpp_addf<0x4E>(s);                                           \
            s = dpp_addf<0x141>(s);                                          \
            const float p = (k < nb) ? exp2f(s) : 0.f;                       \
            den += p;                                                        \
            const _Float16 wh = (_Float16)(p * nm[k]);                       \
            h2 w2 = {wh, wh};                                                \
            acc.h[0] += w2 * xa.h[0];                                        \
            acc.h[1] += w2 * xa.h[1];                                        \
            acc.h[2] += w2 * xa.h[2];                                        \
            acc.h[3] += w2 * xa.h[3];                                        \
        }                                                                    \
    }

// Plain agnn (layers 1-3): writes xn + nrm for the next layer.
__global__ __launch_bounds__(256, 6) void agnn_layer(const uint4* __restrict__ xn4,
                                                     const float* __restrict__ nrm,
                                                     const int4* __restrict__ meta,
                                                     const int* __restrict__ col,
                                                     uint4* __restrict__ xo4,
                                                     float* __restrict__ nrmo,
                                                     int N) {
    const int tid  = threadIdx.x;
    const int lane = tid & 63;
    const int g    = (lane >> 3) & 1;
    const int sub  = lane & 7;
    const int slot = blockIdx.x * 16 + (tid >> 4);
    if (slot >= N) return;

    const int4 m0 = meta[slot];
    const int i  = m0.x;
    const int p0 = m0.y, p1 = m0.z;

    U4H hi_;
    hi_.u = xn4[(unsigned)i * 8u + sub];
    {
        const _Float16 L2E = (_Float16)1.4426950408889634f;
        h2 l2 = {L2E, L2E};
#pragma unroll
        for (int c = 0; c < 4; ++c) hi_.h[c] *= l2;
    }

    const int mid = p0 + ((p1 - p0 + 1) >> 1);
    int       t   = g ? mid : p0;
    const int e_  = g ? p1  : mid;

    float den = 0.f;
    U4H acc;
    acc.h[0] = mkh2(0.f, 0.f); acc.h[1] = mkh2(0.f, 0.f);
    acc.h[2] = mkh2(0.f, 0.f); acc.h[3] = mkh2(0.f, 0.f);

    AGNN_EDGE_LOOP()

    den = dpp_addf<0x140>(den);
#pragma unroll
    for (int c = 0; c < 4; ++c) {
        UHI a; a.h = acc.h[c];
        UHI b; b.u = (unsigned)__shfl_xor((int)a.u, 8, 64);
        acc.h[c] = a.h + b.h;
    }

    const float id = 1.f / fmaxf(den, 1e-12f);
    float o[8];
#pragma unroll
    for (int c = 0; c < 4; ++c) {
        o[2 * c]     = fmaxf((float)acc.h[c].x * id, 0.f);
        o[2 * c + 1] = fmaxf((float)acc.h[c].y * id, 0.f);
    }

    float s2 = 0.f;
#pragma unroll
    for (int c = 0; c < 8; ++c) s2 = fmaf(o[c], o[c], s2);
    s2 = dpp_addf<0xB1>(s2);
    s2 = dpp_addf<0x4E>(s2);
    s2 = dpp_addf<0x141>(s2);
    const float nn  = sqrtf(s2) + 1e-12f;
    const float inv = 1.f / nn;

    if (g == 0) {
        U4H ov;
        ov.h[0] = mkh2(o[0] * inv, o[1] * inv);
        ov.h[1] = mkh2(o[2] * inv, o[3] * inv);
        ov.h[2] = mkh2(o[4] * inv, o[5] * inv);
        ov.h[3] = mkh2(o[6] * inv, o[7] * inv);
        xo4[(unsigned)i * 8u + sub] = ov.u;
        if (sub == 0) nrmo[i] = nn;
    }
}

// Layer 4 + gemm2 fused: out[i,:64] = o_i @ W2^T + b2 from f32 o directly.
// W2 staged TRANSPOSED in LDS: W2T[k][j], row stride 68 floats (16B-aligned,
// 2-way bank aliasing only). o staged per quarter in oL[16][68].
// Lane-in-quarter il computes outputs 4*il..4*il+3.
__global__ __launch_bounds__(256, 6) void agnn_gemm2(const uint4* __restrict__ xn4,
                                                     const float* __restrict__ nrm,
                                                     const int4* __restrict__ meta,
                                                     const int* __restrict__ col,
                                                     const float* __restrict__ W2,
                                                     const float* __restrict__ b2,
                                                     float* __restrict__ out,
                                                     int N) {
    __shared__ __align__(16) float W2T[64 * 68];   // 17 KiB, [k][j] stride 68
    __shared__ __align__(16) float oL[16][68];     // 4.25 KiB
    const int tid  = threadIdx.x;
    const int lane = tid & 63;
    const int g    = (lane >> 3) & 1;
    const int sub  = lane & 7;
    const int q    = tid >> 4;         // quarter within block [0,16)
    const int il   = tid & 15;         // lane within quarter
    const int slot = blockIdx.x * 16 + q;
    const bool slotOK = slot < N;

    // stage W2^T (all threads, unconditional)
    {
        const float4* src = (const float4*)W2;
#pragma unroll
        for (int i2 = 0; i2 < 4; ++i2) {
            int idx = tid + i2 * 256;            // [0,1024) float4 of 64x64
            int j = idx >> 4, k4 = idx & 15;
            float4 v = src[idx];
            W2T[(4 * k4 + 0) * 68 + j] = v.x;
            W2T[(4 * k4 + 1) * 68 + j] = v.y;
            W2T[(4 * k4 + 2) * 68 + j] = v.z;
            W2T[(4 * k4 + 3) * 68 + j] = v.w;
        }
    }

    int nid = 0;
    if (slotOK) {
        const int4 m0 = meta[slot];
        nid = m0.x;
        const int p0 = m0.y, p1 = m0.z;
        const int i = nid;

        U4H hi_;
        hi_.u = xn4[(unsigned)i * 8u + sub];
        {
            const _Float16 L2E = (_Float16)1.4426950408889634f;
            h2 l2 = {L2E, L2E};
#pragma unroll
            for (int c = 0; c < 4; ++c) hi_.h[c] *= l2;
        }

        const int mid = p0 + ((p1 - p0 + 1) >> 1);
        int       t   = g ? mid : p0;
        const int e_  = g ? p1  : mid;

        float den = 0.f;
        U4H acc;
        acc.h[0] = mkh2(0.f, 0.f); acc.h[1] = mkh2(0.f, 0.f);
        acc.h[2] = mkh2(0.f, 0.f); acc.h[3] = mkh2(0.f, 0.f);

        AGNN_EDGE_LOOP()

        den = dpp_addf<0x140>(den);
#pragma unroll
        for (int c = 0; c < 4; ++c) {
            UHI a; a.h = acc.h[c];
            UHI b; b.u = (unsigned)__shfl_xor((int)a.u, 8, 64);
            acc.h[c] = a.h + b.h;
        }

        const float id = 1.f / fmaxf(den, 1e-12f);
        float o[8];
#pragma unroll
        for (int c = 0; c < 4; ++c) {
            o[2 * c]     = fmaxf((float)acc.h[c].x * id, 0.f);
            o[2 * c + 1] = fmaxf((float)acc.h[c].y * id, 0.f);
        }

        // stage this node's f32 o (h4, pre-gemm) into oL; no f16 rounding
        if (g == 0) {
            oL[q][8 * sub + 0] = o[0];
            oL[q][8 * sub + 1] = o[1];
            oL[q][8 * sub + 2] = o[2];
            oL[q][8 * sub + 3] = o[3];
            oL[q][8 * sub + 4] = o[4];
            oL[q][8 * sub + 5] = o[5];
            oL[q][8 * sub + 6] = o[6];
            oL[q][8 * sub + 7] = o[7];
        }
    }

    __syncthreads();   // W2T + oL visible to all

    if (slotOK) {
        float4 res = ((const float4*)b2)[il];
#pragma unroll 4
        for (int kk = 0; kk < 16; ++kk) {
            const float4 o4 = *(const float4*)&oL[q][4 * kk];
#pragma unroll
            for (int c = 0; c < 4; ++c) {
                const int k = 4 * kk + c;
                const float4 w4 = *(const float4*)&W2T[k * 68 + 4 * il];
                const float ok = (c == 0) ? o4.x : (c == 1) ? o4.y
                               : (c == 2) ? o4.z : o4.w;
                res.x = fmaf(ok, w4.x, res.x);
                res.y = fmaf(ok, w4.y, res.y);
                res.z = fmaf(ok, w4.z, res.z);
                res.w = fmaf(ok, w4.w, res.w);
            }
        }
        *(float4*)&out[(size_t)nid * 64 + 4 * il] = res;
    }
}

extern "C" void kernel_launch(void* const* d_in, const int* in_sizes, int n_in,
                              void* d_out, int out_size, void* d_ws, size_t ws_size,
                              hipStream_t stream) {
    const float* x   = (const float*)d_in[0];
    const int*   row = (const int*)d_in[1];
    const int*   col = (const int*)d_in[2];
    const float* W1  = (const float*)d_in[3];
    const float* b1  = (const float*)d_in[4];
    const float* W2  = (const float*)d_in[5];
    const float* b2  = (const float*)d_in[6];
    float* out = (float*)d_out;

    const int N = in_sizes[0] / 128;
    const int E = in_sizes[1];

    char* ws = (char*)d_ws;
    size_t off = 0;
    unsigned short* ha = (unsigned short*)(ws + off); off += (size_t)N * 64 * 2;
    unsigned short* hb = (unsigned short*)(ws + off); off += (size_t)N * 64 * 2;
    float* na_  = (float*)(ws + off); off += (size_t)N * sizeof(float);
    float* nb_  = (float*)(ws + off); off += (size_t)N * sizeof(float);
    off = (off + 15) & ~(size_t)15;
    int4*  meta = (int4*) (ws + off); off += (size_t)N * sizeof(int4);
    (void)ws_size; (void)n_in; (void)out_size;

    // fused rowptr(binsearch) + degree sort -> meta
    build_meta_sort<<<(N + PSEG - 1) / PSEG, 1024, 0, stream>>>(row, meta, N, E);

    const int nbG = (N + 63) / 64;
    gemm1_relu<<<nbG, 256, 0, stream>>>(x, W1, b1, ha, na_, N);

    const int nb16 = (N + 15) / 16;
    unsigned short* hc = ha; unsigned short* hn = hb;
    float* nc = na_; float* nn = nb_;
    for (int l = 0; l < 3; ++l) {
        agnn_layer<<<nb16, 256, 0, stream>>>((const uint4*)hc, nc, meta, col,
                                             (uint4*)hn, nn, N);
        unsigned short* t = hc; hc = hn; hn = t;
        float* tf = nc; nc = nn; nn = tf;
    }

    // layer 4 + gemm2 fused
    agnn_gemm2<<<nb16, 256, 0, stream>>>((const uint4*)hc, nc, meta, col,
                                         W2, b2, out, N);
}